// Round 6
// baseline (1431.066 us; speedup 1.0000x reference)
//
#include <hip/hip_runtime.h>
#include <cstdint>

#define DD 128
#define NBLK 512
#define NTHR 256
#define NTOT (NBLK * NTHR)
#define NWAVE (NTOT / 64)
#define CAP 128
#define E0C 480000
#define E1C 96000
#define N0C 120000
#define N1C 30000
#define N2C 6000

typedef unsigned short u16;
typedef __attribute__((ext_vector_type(8))) short bf16x8;
typedef __attribute__((ext_vector_type(16))) float f32x16;

__device__ __forceinline__ u16 f2b(float f) {
    union { float f; unsigned u; } a; a.f = f;
    unsigned r = (a.u + 0x7fffu + ((a.u >> 16) & 1u)) >> 16;
    return (u16)r;
}
__device__ __forceinline__ float b2f(u16 u) {
    union { unsigned u; float f; } a; a.u = ((unsigned)u) << 16;
    return a.f;
}
__device__ __forceinline__ bf16x8 cvt8(float4 u0, float4 u1) {
    bf16x8 r;
    r[0] = (short)f2b(u0.x); r[1] = (short)f2b(u0.y);
    r[2] = (short)f2b(u0.z); r[3] = (short)f2b(u0.w);
    r[4] = (short)f2b(u1.x); r[5] = (short)f2b(u1.y);
    r[6] = (short)f2b(u1.z); r[7] = (short)f2b(u1.w);
    return r;
}

struct Args {
    const float* x;
    const int *src0, *dst0, *eid0, *src1, *dst1, *eid1, *etype;
    const float *preb, *bias0, *g0, *be0, *bias1, *g1, *be1, *postb;
    const float *comp0, *comp1;
    const float* wsrc[12];
    u16 *h0, *T0, *h1, *T1, *h2, *wt;
    int *cnt0, *cnt1, *ep0, *ep1, *bar;
    float* out;
};

// sense-reversing grid barrier; all NBLK blocks co-resident (2/CU).
__device__ __forceinline__ void gbar(int* bar)
{
    __syncthreads();
    if (threadIdx.x == 0) {
        __threadfence();   // agent-scope fence: publish this block's writes
        int gen = __hip_atomic_load(&bar[1], __ATOMIC_RELAXED, __HIP_MEMORY_SCOPE_AGENT);
        int arrived = __hip_atomic_fetch_add(&bar[0], 1, __ATOMIC_ACQ_REL, __HIP_MEMORY_SCOPE_AGENT);
        if (arrived == NBLK - 1) {
            __hip_atomic_store(&bar[0], 0, __ATOMIC_RELAXED, __HIP_MEMORY_SCOPE_AGENT);
            __hip_atomic_store(&bar[1], gen + 1, __ATOMIC_RELEASE, __HIP_MEMORY_SCOPE_AGENT);
        } else {
            while (__hip_atomic_load(&bar[1], __ATOMIC_ACQUIRE, __HIP_MEMORY_SCOPE_AGENT) == gen)
                __builtin_amdgcn_s_sleep(2);
        }
    }
    __syncthreads();
}

// 32x32x16 MFMA GEMM phase: C = sum_p Ap[p]@Wp[p] + Ar@Wr + bias [+LN/ReLU]
// W in fragment order. A: [row][k]. C/D: col=lane&31, row=(reg&3)+8*(reg>>2)+4*(lane>>5).
template<bool OBF16, bool AF32, bool LN, bool RELU>
__device__ void gemm_phase(const u16* Ap, int nplanes, const void* Ar,
                           const u16* Wp, const u16* Wr,
                           const float* bias, const float* gw, const float* bw,
                           void* Cv, int nrows, int wid, int lane)
{
    int l31 = lane & 31, half = lane >> 5;
    int ntile = (nrows + 31) >> 5;
    for (int tile = wid; tile < ntile; tile += NWAVE) {
        int m0 = tile * 32;
        int arow = m0 + l31;
        bool rv = arow < nrows;
        f32x16 acc[4];
        #pragma unroll
        for (int t = 0; t < 4; ++t)
            #pragma unroll
            for (int i = 0; i < 16; ++i) acc[t][i] = 0.f;

        if (AF32) {
            bf16x8 A0[8];
            if (rv) {
                const float* Aq = (const float*)Ar + (size_t)arow * DD;
                float4 st[8];
                #pragma unroll
                for (int c = 0; c < 8; ++c)
                    st[c] = *(const float4*)(Aq + (c >> 1) * 16 + half * 8 + (c & 1) * 4);
                #pragma unroll
                for (int c = 0; c < 4; ++c) A0[c] = cvt8(st[2 * c], st[2 * c + 1]);
                #pragma unroll
                for (int c = 0; c < 8; ++c)
                    st[c] = *(const float4*)(Aq + 64 + (c >> 1) * 16 + half * 8 + (c & 1) * 4);
                #pragma unroll
                for (int c = 0; c < 4; ++c) A0[4 + c] = cvt8(st[2 * c], st[2 * c + 1]);
            } else {
                #pragma unroll
                for (int c = 0; c < 8; ++c) A0[c] = (bf16x8){0,0,0,0,0,0,0,0};
            }
            #pragma unroll
            for (int kc = 0; kc < 8; ++kc) {
                bf16x8 bfr[4];
                #pragma unroll
                for (int t = 0; t < 4; ++t)
                    bfr[t] = *(const bf16x8*)(Wr + (size_t)((kc * 4 + t) * 64 + lane) * 8);
                #pragma unroll
                for (int t = 0; t < 4; ++t)
                    acc[t] = __builtin_amdgcn_mfma_f32_32x32x16_bf16(A0[kc], bfr[t], acc[t], 0, 0, 0);
            }
        } else {
            bf16x8 A0[8], A1[8];
            {
                const u16* Ainit = (nplanes == 0) ? (const u16*)Ar : Ap;
                if (rv) {
                    #pragma unroll
                    for (int c = 0; c < 8; ++c)
                        A0[c] = *(const bf16x8*)(Ainit + (size_t)arow * DD + c * 16 + half * 8);
                } else {
                    #pragma unroll
                    for (int c = 0; c < 8; ++c) A0[c] = (bf16x8){0,0,0,0,0,0,0,0};
                }
            }
            for (int p = 0; p <= nplanes; ++p) {
                const u16* Wsel = (p == nplanes) ? Wr : Wp + p * 16384;
                if (p < nplanes) {
                    const u16* An = (p + 1 == nplanes) ? (const u16*)Ar
                                                       : Ap + (size_t)(p + 1) * nrows * DD;
                    if (rv) {
                        #pragma unroll
                        for (int c = 0; c < 8; ++c)
                            A1[c] = *(const bf16x8*)(An + (size_t)arow * DD + c * 16 + half * 8);
                    } else {
                        #pragma unroll
                        for (int c = 0; c < 8; ++c) A1[c] = (bf16x8){0,0,0,0,0,0,0,0};
                    }
                }
                #pragma unroll
                for (int kc = 0; kc < 8; ++kc) {
                    bf16x8 bfr[4];
                    #pragma unroll
                    for (int t = 0; t < 4; ++t)
                        bfr[t] = *(const bf16x8*)(Wsel + (size_t)((kc * 4 + t) * 64 + lane) * 8);
                    #pragma unroll
                    for (int t = 0; t < 4; ++t)
                        acc[t] = __builtin_amdgcn_mfma_f32_32x32x16_bf16(A0[kc], bfr[t], acc[t], 0, 0, 0);
                }
                if (p < nplanes) {
                    #pragma unroll
                    for (int c = 0; c < 8; ++c) A0[c] = A1[c];
                }
            }
        }

        float bb[4];
        #pragma unroll
        for (int t = 0; t < 4; ++t) bb[t] = bias[t * 32 + l31];
        float gg[4], ww[4];
        if (LN) {
            #pragma unroll
            for (int t = 0; t < 4; ++t) { gg[t] = gw[t * 32 + l31]; ww[t] = bw[t * 32 + l31]; }
        }
        #pragma unroll
        for (int reg = 0; reg < 16; ++reg) {
            int rl = (reg & 3) + 8 * (reg >> 2) + 4 * half;
            int row = m0 + rl;
            float v[4];
            #pragma unroll
            for (int t = 0; t < 4; ++t) v[t] = acc[t][reg] + bb[t];
            if (LN) {
                float s1 = 0.f, s2 = 0.f;
                #pragma unroll
                for (int t = 0; t < 4; ++t) { s1 += v[t]; s2 += v[t] * v[t]; }
                #pragma unroll
                for (int o = 1; o < 32; o <<= 1) {
                    s1 += __shfl_xor(s1, o);
                    s2 += __shfl_xor(s2, o);
                }
                float mu = s1 * (1.f / 128.f);
                float var = s2 * (1.f / 128.f) - mu * mu;
                float rstd = rsqrtf(fmaxf(var, 0.f) + 1e-5f);
                #pragma unroll
                for (int t = 0; t < 4; ++t) v[t] = (v[t] - mu) * rstd * gg[t] + ww[t];
            }
            if (RELU || LN) {
                #pragma unroll
                for (int t = 0; t < 4; ++t) v[t] = fmaxf(v[t], 0.f);
            }
            if (row < nrows) {
                #pragma unroll
                for (int t = 0; t < 4; ++t) {
                    if (OBF16) ((u16*)Cv)[(size_t)row * DD + t * 32 + l31] = f2b(v[t]);
                    else       ((float*)Cv)[(size_t)row * DD + t * 32 + l31] = v[t];
                }
            }
        }
    }
}

// gather-aggregate into 4 basis planes with 1/deg folded in
__device__ void agg_phase(const u16* __restrict__ h, const int* __restrict__ cnt,
                          const int* __restrict__ ep, const float4* cmp4s,
                          u16* __restrict__ T, int ndst, int wid, int lane)
{
    for (int row = wid; row < ndst; row += NWAVE) {
        int n = cnt[row];
        int end = n < CAP ? n : CAP;
        const int* erow = ep + (size_t)row * CAP;
        float a0[4] = {0.f, 0.f, 0.f, 0.f};
        float a1[4] = {0.f, 0.f, 0.f, 0.f};
        int j = 0;
        for (; j + 8 <= end; j += 8) {
            int vv[8]; unsigned gg[8];
            #pragma unroll
            for (int u = 0; u < 8; ++u) vv[u] = erow[j + u];
            #pragma unroll
            for (int u = 0; u < 8; ++u)
                gg[u] = *(const unsigned*)(h + (size_t)(vv[u] & 0x0FFFFFFF) * DD + 2 * lane);
            #pragma unroll
            for (int u = 0; u < 8; ++u) {
                float4 c = cmp4s[vv[u] >> 28];
                float x0 = b2f((u16)(gg[u] & 0xffffu));
                float x1 = b2f((u16)(gg[u] >> 16));
                a0[0] = fmaf(c.x, x0, a0[0]); a1[0] = fmaf(c.x, x1, a1[0]);
                a0[1] = fmaf(c.y, x0, a0[1]); a1[1] = fmaf(c.y, x1, a1[1]);
                a0[2] = fmaf(c.z, x0, a0[2]); a1[2] = fmaf(c.z, x1, a1[2]);
                a0[3] = fmaf(c.w, x0, a0[3]); a1[3] = fmaf(c.w, x1, a1[3]);
            }
        }
        for (; j < end; ++j) {
            int v = erow[j];
            unsigned g = *(const unsigned*)(h + (size_t)(v & 0x0FFFFFFF) * DD + 2 * lane);
            float4 c = cmp4s[v >> 28];
            float x0 = b2f((u16)(g & 0xffffu));
            float x1 = b2f((u16)(g >> 16));
            a0[0] = fmaf(c.x, x0, a0[0]); a1[0] = fmaf(c.x, x1, a1[0]);
            a0[1] = fmaf(c.y, x0, a0[1]); a1[1] = fmaf(c.y, x1, a1[1]);
            a0[2] = fmaf(c.z, x0, a0[2]); a1[2] = fmaf(c.z, x1, a1[2]);
            a0[3] = fmaf(c.w, x0, a0[3]); a1[3] = fmaf(c.w, x1, a1[3]);
        }
        float inv = 1.f / fmaxf((float)n, 1.f);
        #pragma unroll
        for (int b = 0; b < 4; ++b) {
            unsigned pk = (unsigned)f2b(a0[b] * inv) | ((unsigned)f2b(a1[b] * inv) << 16);
            *(unsigned*)(T + ((size_t)b * ndst + row) * DD + 2 * lane) = pk;
        }
    }
}

__global__ __launch_bounds__(NTHR, 2) void mega(Args a)
{
    __shared__ float tile[32][33];
    __shared__ float4 cmp4s[8];
    int tid = threadIdx.x, bid = blockIdx.x;
    int gtid = bid * NTHR + tid;
    int wid = gtid >> 6, lane = tid & 63;

    // ---- P0: zero counters + weight convert/transpose ----
    for (int i = gtid; i < N1C + N2C; i += NTOT) {
        if (i < N1C) a.cnt0[i] = 0; else a.cnt1[i - N1C] = 0;
    }
    if (bid < 192) {
        const float* src = a.wsrc[bid >> 4];
        int t4 = bid & 15;
        int tr = (t4 >> 2) * 32, tc = (t4 & 3) * 32;
        int lx = tid & 31, ly = tid >> 5;
        #pragma unroll
        for (int yy = 0; yy < 32; yy += 8)
            tile[ly + yy][lx] = src[(tr + ly + yy) * DD + tc + lx];
        __syncthreads();
        if (tid < 128) {
            int nl = tid >> 2, kch = tid & 3;
            int k = tr + kch * 8, n = tc + nl;
            int kc = k >> 4, half = (k >> 3) & 1;
            int t = n >> 5, l31 = n & 31;
            bf16x8 pk;
            #pragma unroll
            for (int j = 0; j < 8; ++j) pk[j] = (short)f2b(tile[kch * 8 + j][nl]);
            *(bf16x8*)(a.wt + (size_t)(bid >> 4) * 16384 + kc * 2048 + t * 512 + half * 256 + l31 * 8) = pk;
        }
    }
    gbar(a.bar);

    // ---- P1: bucket-fill (both layers) + pre-GEMM ----
    for (int e = gtid; e < E0C + E1C; e += NTOT) {
        bool L0 = e < E0C;
        int ee = L0 ? e : e - E0C;
        int d   = L0 ? a.dst0[ee] : a.dst1[ee];
        int eid = L0 ? a.eid0[ee] : a.eid1[ee];
        int s   = L0 ? a.src0[ee] : a.src1[ee];
        int r = a.etype[eid];
        int* cnt = L0 ? a.cnt0 : a.cnt1;
        int* ep  = L0 ? a.ep0  : a.ep1;
        int pos = atomicAdd(&cnt[d], 1);
        if (pos < CAP) ep[(size_t)d * CAP + pos] = s | (r << 28);
    }
    gemm_phase<true, true, false, true>(nullptr, 0, a.x, nullptr, a.wt,
        a.preb, nullptr, nullptr, a.h0, N0C, wid, lane);
    gbar(a.bar);

    // ---- P2: agg layer 0 ----
    if (tid < 8) cmp4s[tid] = ((const float4*)a.comp0)[tid];
    __syncthreads();
    agg_phase(a.h0, a.cnt0, a.ep0, cmp4s, a.T0, N1C, wid, lane);
    gbar(a.bar);

    // ---- P3: conv0 + LN + ReLU ----
    gemm_phase<true, false, true, false>(a.T0, 4, a.h0, a.wt + 1 * 16384, a.wt + 5 * 16384,
        a.bias0, a.g0, a.be0, a.h1, N1C, wid, lane);
    gbar(a.bar);

    // ---- P4: agg layer 1 ----
    if (tid < 8) cmp4s[tid] = ((const float4*)a.comp1)[tid];
    __syncthreads();
    agg_phase(a.h1, a.cnt1, a.ep1, cmp4s, a.T1, N2C, wid, lane);
    gbar(a.bar);

    // ---- P5: conv1 + LN + ReLU ----
    gemm_phase<true, false, true, false>(a.T1, 4, a.h1, a.wt + 6 * 16384, a.wt + 10 * 16384,
        a.bias1, a.g1, a.be1, a.h2, N2C, wid, lane);
    gbar(a.bar);

    // ---- P6: post GEMM -> f32 out ----
    gemm_phase<false, false, false, false>(nullptr, 0, a.h2, nullptr, a.wt + 11 * 16384,
        a.postb, nullptr, nullptr, a.out, N2C, wid, lane);
}

extern "C" void kernel_launch(void* const* d_in, const int* in_sizes, int n_in,
                              void* d_out, int out_size, void* d_ws, size_t ws_size,
                              hipStream_t stream)
{
    Args a;
    a.x     = (const float*)d_in[0];
    a.src0  = (const int*)d_in[1];
    a.dst0  = (const int*)d_in[2];
    a.eid0  = (const int*)d_in[3];
    a.src1  = (const int*)d_in[4];
    a.dst1  = (const int*)d_in[5];
    a.eid1  = (const int*)d_in[6];
    a.etype = (const int*)d_in[7];
    const float* preW   = (const float*)d_in[8];
    a.preb  = (const float*)d_in[9];
    const float* basis0 = (const float*)d_in[10];
    a.comp0 = (const float*)d_in[11];
    const float* root0  = (const float*)d_in[12];
    a.bias0 = (const float*)d_in[13];
    a.g0    = (const float*)d_in[14];
    a.be0   = (const float*)d_in[15];
    const float* basis1 = (const float*)d_in[16];
    a.comp1 = (const float*)d_in[17];
    const float* root1  = (const float*)d_in[18];
    a.bias1 = (const float*)d_in[19];
    a.g1    = (const float*)d_in[20];
    a.be1   = (const float*)d_in[21];
    const float* postW  = (const float*)d_in[22];
    a.postb = (const float*)d_in[23];
    a.out   = (float*)d_out;

    a.wsrc[0] = preW;
    for (int b = 0; b < 4; ++b) a.wsrc[1 + b] = basis0 + (size_t)b * 16384;
    a.wsrc[5] = root0;
    for (int b = 0; b < 4; ++b) a.wsrc[6 + b] = basis1 + (size_t)b * 16384;
    a.wsrc[10] = root1;
    a.wsrc[11] = postW;

    char* ws = (char*)d_ws;
    size_t o = 0;
    auto alloc = [&](size_t bytes) { char* p = ws + o; o += (bytes + 255) & ~(size_t)255; return p; };
    a.h0   = (u16*)alloc((size_t)N0C * DD * 2);
    a.T0   = (u16*)alloc((size_t)4 * N1C * DD * 2);
    a.h1   = (u16*)alloc((size_t)N1C * DD * 2);
    a.T1   = (u16*)alloc((size_t)4 * N2C * DD * 2);
    a.h2   = (u16*)alloc((size_t)N2C * DD * 2);
    a.wt   = (u16*)alloc((size_t)12 * 16384 * 2);
    a.cnt0 = (int*)alloc((size_t)N1C * 4);
    a.cnt1 = (int*)alloc((size_t)N2C * 4);
    a.ep0  = (int*)alloc((size_t)N1C * CAP * 4);
    a.ep1  = (int*)alloc((size_t)N2C * CAP * 4);
    a.bar  = (int*)alloc(256);

    hipMemsetAsync(a.bar, 0, 64, stream);
    mega<<<NBLK, NTHR, 0, stream>>>(a);
}

// Round 7
// 305.050 us; speedup vs baseline: 4.6912x; 4.6912x over previous
//
#include <hip/hip_runtime.h>
#include <cstdint>

#define DD 128
#define CAP 64
#define E0C 480000
#define E1C 96000
#define N0C 120000
#define N1C 30000
#define N2C 6000

typedef unsigned short u16;
typedef __attribute__((ext_vector_type(8))) short bf16x8;
typedef __attribute__((ext_vector_type(16))) float f32x16;

__device__ __forceinline__ u16 f2b(float f) {
    union { float f; unsigned u; } a; a.f = f;
    unsigned r = (a.u + 0x7fffu + ((a.u >> 16) & 1u)) >> 16;
    return (u16)r;
}
__device__ __forceinline__ float b2f(u16 u) {
    union { unsigned u; float f; } a; a.u = ((unsigned)u) << 16;
    return a.f;
}

// ---- K1: weight convert+transpose into MFMA fragment order + zero counters ----
// wt layout (shorts): mat*16384 + kc*2048 + t*512 + half*256 + l31*8 + j
// where n = t*32+l31, k = kc*16+half*8+j. B-frag load in GEMM is then
// base + ((kc*4+t)*64 + lane)*8 -> lane-consecutive 16B, perfectly coalesced.
struct WtJob { const float* src[12]; };
__global__ __launch_bounds__(256) void prep_kernel(
    WtJob job, u16* __restrict__ dst, int* __restrict__ cnt0, int* __restrict__ cnt1)
{
    int gtid = blockIdx.x * 256 + threadIdx.x;
    for (int i = gtid; i < N1C + N2C; i += 256 * 256) {
        if (i < N1C) cnt0[i] = 0; else cnt1[i - N1C] = 0;
    }
    if (blockIdx.x >= 192) return;
    __shared__ float tile[32][33];
    int m = blockIdx.x >> 4;
    int t4 = blockIdx.x & 15;
    int tr = (t4 >> 2) * 32;   // k-base
    int tc = (t4 & 3) * 32;    // n-base
    int lx = threadIdx.x & 31, ly = threadIdx.x >> 5;
    #pragma unroll
    for (int yy = 0; yy < 32; yy += 8)
        tile[ly + yy][lx] = job.src[m][(tr + ly + yy) * DD + tc + lx];
    __syncthreads();
    int tid = threadIdx.x;
    if (tid < 128) {
        int nl = tid >> 2, kch = tid & 3;
        int k = tr + kch * 8, n = tc + nl;
        int kc = k >> 4, half = (k >> 3) & 1;
        int t = n >> 5, l31 = n & 31;
        bf16x8 pk;
        #pragma unroll
        for (int j = 0; j < 8; ++j) pk[j] = (short)f2b(tile[kch * 8 + j][nl]);
        *(bf16x8*)(dst + (size_t)m * 16384 + kc * 2048 + t * 512 + half * 256 + l31 * 8) = pk;
    }
}

// ---- K2: bucket fill (both layers), atomic append; no scan needed ----
__global__ __launch_bounds__(256) void fill_kernel(
    const int* __restrict__ src0, const int* __restrict__ dst0, const int* __restrict__ eid0,
    const int* __restrict__ src1, const int* __restrict__ dst1, const int* __restrict__ eid1,
    const int* __restrict__ etype,
    int* __restrict__ cnt0, int* __restrict__ cnt1,
    int* __restrict__ ep0, int* __restrict__ ep1)
{
    int e = blockIdx.x * 256 + threadIdx.x;
    bool L0 = e < E0C;
    int ee = L0 ? e : e - E0C;
    if (!L0 && ee >= E1C) return;
    int d   = L0 ? dst0[ee] : dst1[ee];
    int eid = L0 ? eid0[ee] : eid1[ee];
    int s   = L0 ? src0[ee] : src1[ee];
    int r = etype[eid];
    int* cnt = L0 ? cnt0 : cnt1;
    int* ep  = L0 ? ep0  : ep1;
    int pos = atomicAdd(&cnt[d], 1);
    if (pos < CAP) ep[(size_t)d * CAP + pos] = s | (r << 28);
}

// ---- gather-aggregate into 4 basis planes, 1/deg folded in ----
__global__ __launch_bounds__(256) void agg_kernel(
    const u16* __restrict__ h, const int* __restrict__ cnt,
    const int* __restrict__ ep, const float* __restrict__ comp,
    u16* __restrict__ T, int ndst)
{
    __shared__ float4 cmp4[8];
    if (threadIdx.x < 8) cmp4[threadIdx.x] = ((const float4*)comp)[threadIdx.x];
    __syncthreads();
    int row = blockIdx.x * 4 + (threadIdx.x >> 6);
    if (row >= ndst) return;
    int lane = threadIdx.x & 63;
    int n = cnt[row];
    int end = n < CAP ? n : CAP;
    const int* erow = ep + (size_t)row * CAP;
    float a0[4] = {0.f, 0.f, 0.f, 0.f};
    float a1[4] = {0.f, 0.f, 0.f, 0.f};
    int j = 0;
    for (; j + 8 <= end; j += 8) {
        int vv[8]; unsigned gg[8];
        #pragma unroll
        for (int u = 0; u < 8; ++u) vv[u] = erow[j + u];
        #pragma unroll
        for (int u = 0; u < 8; ++u)
            gg[u] = *(const unsigned*)(h + (size_t)(vv[u] & 0x0FFFFFFF) * DD + 2 * lane);
        #pragma unroll
        for (int u = 0; u < 8; ++u) {
            float4 c = cmp4[vv[u] >> 28];
            float x0 = b2f((u16)(gg[u] & 0xffffu));
            float x1 = b2f((u16)(gg[u] >> 16));
            a0[0] = fmaf(c.x, x0, a0[0]); a1[0] = fmaf(c.x, x1, a1[0]);
            a0[1] = fmaf(c.y, x0, a0[1]); a1[1] = fmaf(c.y, x1, a1[1]);
            a0[2] = fmaf(c.z, x0, a0[2]); a1[2] = fmaf(c.z, x1, a1[2]);
            a0[3] = fmaf(c.w, x0, a0[3]); a1[3] = fmaf(c.w, x1, a1[3]);
        }
    }
    for (; j < end; ++j) {
        int v = erow[j];
        unsigned g = *(const unsigned*)(h + (size_t)(v & 0x0FFFFFFF) * DD + 2 * lane);
        float4 c = cmp4[v >> 28];
        float x0 = b2f((u16)(g & 0xffffu));
        float x1 = b2f((u16)(g >> 16));
        a0[0] = fmaf(c.x, x0, a0[0]); a1[0] = fmaf(c.x, x1, a1[0]);
        a0[1] = fmaf(c.y, x0, a0[1]); a1[1] = fmaf(c.y, x1, a1[1]);
        a0[2] = fmaf(c.z, x0, a0[2]); a1[2] = fmaf(c.z, x1, a1[2]);
        a0[3] = fmaf(c.w, x0, a0[3]); a1[3] = fmaf(c.w, x1, a1[3]);
    }
    float inv = 1.f / fmaxf((float)n, 1.f);
    #pragma unroll
    for (int b = 0; b < 4; ++b) {
        unsigned pk = (unsigned)f2b(a0[b] * inv) | ((unsigned)f2b(a1[b] * inv) << 16);
        *(unsigned*)(T + ((size_t)b * ndst + row) * DD + 2 * lane) = pk;
    }
}

// ---- 32x32x16 MFMA GEMM, one 32-row m-tile per wave, A prefetched ----
// C[nrows x 128] = sum_p Ap[p]@Wp[p] + Ar@Wr + bias, optional LN/ReLU.
// W in fragment order (see prep). A: [row][k].
// C/D layout: col=lane&31, row=(reg&3)+8*(reg>>2)+4*(lane>>5)  [m74/m101].
template<int WPB, bool OBF16, bool RELU, bool AF32, bool LN>
__global__ __launch_bounds__(WPB * 64) void mfma_gemm(
    const u16* __restrict__ Ap, int nplanes, const void* __restrict__ Ar,
    const u16* __restrict__ Wp, const u16* __restrict__ Wr,
    const float* __restrict__ bias, const float* __restrict__ gw,
    const float* __restrict__ bw, void* __restrict__ Cv, int nrows)
{
    int wave = threadIdx.x >> 6;
    int lane = threadIdx.x & 63;
    int l31 = lane & 31, half = lane >> 5;
    int m0 = (blockIdx.x * WPB + wave) * 32;
    int arow = m0 + l31;
    bool rv = arow < nrows;
    f32x16 acc[4];
    #pragma unroll
    for (int t = 0; t < 4; ++t)
        #pragma unroll
        for (int i = 0; i < 16; ++i) acc[t][i] = 0.f;

    if (AF32) {
        const float* Aq = (const float*)Ar + (size_t)arow * DD;
        float4 st[16];
        if (rv) {
            #pragma unroll
            for (int c = 0; c < 16; ++c)
                st[c] = *(const float4*)(Aq + ((c >> 1) * 16 + half * 8) + (c & 1) * 4);
        } else {
            #pragma unroll
            for (int c = 0; c < 16; ++c) st[c] = make_float4(0.f, 0.f, 0.f, 0.f);
        }
        #pragma unroll
        for (int kc = 0; kc < 8; ++kc) {
            bf16x8 bfr[4];
            #pragma unroll
            for (int t = 0; t < 4; ++t)
                bfr[t] = *(const bf16x8*)(Wr + (size_t)((kc * 4 + t) * 64 + lane) * 8);
            float4 u0 = st[2 * kc], u1 = st[2 * kc + 1];
            bf16x8 af;
            af[0] = (short)f2b(u0.x); af[1] = (short)f2b(u0.y);
            af[2] = (short)f2b(u0.z); af[3] = (short)f2b(u0.w);
            af[4] = (short)f2b(u1.x); af[5] = (short)f2b(u1.y);
            af[6] = (short)f2b(u1.z); af[7] = (short)f2b(u1.w);
            #pragma unroll
            for (int t = 0; t < 4; ++t)
                acc[t] = __builtin_amdgcn_mfma_f32_32x32x16_bf16(af, bfr[t], acc[t], 0, 0, 0);
        }
    } else {
        bf16x8 A0[8], A1[8];
        {
            const u16* Ainit = (nplanes == 0) ? (const u16*)Ar : Ap;
            if (rv) {
                #pragma unroll
                for (int c = 0; c < 8; ++c)
                    A0[c] = *(const bf16x8*)(Ainit + (size_t)arow * DD + c * 16 + half * 8);
            } else {
                #pragma unroll
                for (int c = 0; c < 8; ++c) A0[c] = (bf16x8){0,0,0,0,0,0,0,0};
            }
        }
        for (int p = 0; p <= nplanes; ++p) {
            const u16* Wsel = (p == nplanes) ? Wr : Wp + p * 16384;
            if (p < nplanes) {
                const u16* An = (p + 1 == nplanes) ? (const u16*)Ar
                                                   : Ap + (size_t)(p + 1) * nrows * DD;
                if (rv) {
                    #pragma unroll
                    for (int c = 0; c < 8; ++c)
                        A1[c] = *(const bf16x8*)(An + (size_t)arow * DD + c * 16 + half * 8);
                } else {
                    #pragma unroll
                    for (int c = 0; c < 8; ++c) A1[c] = (bf16x8){0,0,0,0,0,0,0,0};
                }
            }
            #pragma unroll
            for (int kc = 0; kc < 8; ++kc) {
                bf16x8 bfr[4];
                #pragma unroll
                for (int t = 0; t < 4; ++t)
                    bfr[t] = *(const bf16x8*)(Wsel + (size_t)((kc * 4 + t) * 64 + lane) * 8);
                #pragma unroll
                for (int t = 0; t < 4; ++t)
                    acc[t] = __builtin_amdgcn_mfma_f32_32x32x16_bf16(A0[kc], bfr[t], acc[t], 0, 0, 0);
            }
            if (p < nplanes) {
                #pragma unroll
                for (int c = 0; c < 8; ++c) A0[c] = A1[c];
            }
        }
    }

    float bb[4];
    #pragma unroll
    for (int t = 0; t < 4; ++t) bb[t] = bias[t * 32 + l31];
    float gg[4], ww[4];
    if (LN) {
        #pragma unroll
        for (int t = 0; t < 4; ++t) { gg[t] = gw[t * 32 + l31]; ww[t] = bw[t * 32 + l31]; }
    }

    #pragma unroll
    for (int reg = 0; reg < 16; ++reg) {
        int rl = (reg & 3) + 8 * (reg >> 2) + 4 * half;
        int row = m0 + rl;
        float v[4];
        #pragma unroll
        for (int t = 0; t < 4; ++t) v[t] = acc[t][reg] + bb[t];
        if (LN) {
            float s1 = 0.f, s2 = 0.f;
            #pragma unroll
            for (int t = 0; t < 4; ++t) { s1 += v[t]; s2 += v[t] * v[t]; }
            #pragma unroll
            for (int o = 1; o < 32; o <<= 1) {
                s1 += __shfl_xor(s1, o);
                s2 += __shfl_xor(s2, o);
            }
            float mu = s1 * (1.f / 128.f);
            float var = s2 * (1.f / 128.f) - mu * mu;
            float rstd = rsqrtf(fmaxf(var, 0.f) + 1e-5f);
            #pragma unroll
            for (int t = 0; t < 4; ++t) v[t] = (v[t] - mu) * rstd * gg[t] + ww[t];
        }
        if (RELU || LN) {
            #pragma unroll
            for (int t = 0; t < 4; ++t) v[t] = fmaxf(v[t], 0.f);
        }
        if (row < nrows) {
            #pragma unroll
            for (int t = 0; t < 4; ++t) {
                if (OBF16) ((u16*)Cv)[(size_t)row * DD + t * 32 + l31] = f2b(v[t]);
                else       ((float*)Cv)[(size_t)row * DD + t * 32 + l31] = v[t];
            }
        }
    }
}

extern "C" void kernel_launch(void* const* d_in, const int* in_sizes, int n_in,
                              void* d_out, int out_size, void* d_ws, size_t ws_size,
                              hipStream_t stream)
{
    const float* x     = (const float*)d_in[0];
    const int* src0    = (const int*)d_in[1];
    const int* dst0    = (const int*)d_in[2];
    const int* eid0    = (const int*)d_in[3];
    const int* src1    = (const int*)d_in[4];
    const int* dst1    = (const int*)d_in[5];
    const int* eid1    = (const int*)d_in[6];
    const int* etype   = (const int*)d_in[7];
    const float* preW  = (const float*)d_in[8];
    const float* preb  = (const float*)d_in[9];
    const float* basis0 = (const float*)d_in[10];
    const float* comp0  = (const float*)d_in[11];
    const float* root0  = (const float*)d_in[12];
    const float* bias0  = (const float*)d_in[13];
    const float* g0    = (const float*)d_in[14];
    const float* be0   = (const float*)d_in[15];
    const float* basis1 = (const float*)d_in[16];
    const float* comp1  = (const float*)d_in[17];
    const float* root1  = (const float*)d_in[18];
    const float* bias1  = (const float*)d_in[19];
    const float* g1    = (const float*)d_in[20];
    const float* be1   = (const float*)d_in[21];
    const float* postW = (const float*)d_in[22];
    const float* postb = (const float*)d_in[23];
    float* out = (float*)d_out;

    char* ws = (char*)d_ws;
    size_t o = 0;
    auto alloc = [&](size_t bytes) { char* p = ws + o; o += (bytes + 255) & ~(size_t)255; return p; };
    u16* h0   = (u16*)alloc((size_t)N0C * DD * 2);
    u16* T0   = (u16*)alloc((size_t)4 * N1C * DD * 2);
    u16* h1   = (u16*)alloc((size_t)N1C * DD * 2);
    u16* T1   = (u16*)alloc((size_t)4 * N2C * DD * 2);
    u16* h2   = (u16*)alloc((size_t)N2C * DD * 2);
    u16* wt   = (u16*)alloc((size_t)12 * 16384 * 2);
    int* cnt0 = (int*)alloc((size_t)N1C * 4);
    int* cnt1 = (int*)alloc((size_t)N2C * 4);
    int* ep0  = (int*)alloc((size_t)N1C * CAP * 4);
    int* ep1  = (int*)alloc((size_t)N2C * CAP * 4);

    // wt layout: [0]=pre, [1..4]=basis0, [5]=root0, [6..9]=basis1, [10]=root1, [11]=post
    WtJob job;
    job.src[0] = preW;
    for (int b = 0; b < 4; ++b) job.src[1 + b] = basis0 + (size_t)b * 16384;
    job.src[5] = root0;
    for (int b = 0; b < 4; ++b) job.src[6 + b] = basis1 + (size_t)b * 16384;
    job.src[10] = root1;
    job.src[11] = postW;

    // K1: weight transpose + zero counters
    prep_kernel<<<256, 256, 0, stream>>>(job, wt, cnt0, cnt1);
    // K2: bucket fill (both layers)
    fill_kernel<<<(E0C + E1C + 255) / 256, 256, 0, stream>>>(
        src0, dst0, eid0, src1, dst1, eid1, etype, cnt0, cnt1, ep0, ep1);
    // K3: h0 = relu(x @ preW + preb)
    mfma_gemm<4, true, true, true, false><<<(N0C + 127) / 128, 256, 0, stream>>>(
        nullptr, 0, x, nullptr, wt + 0 * 16384, preb, nullptr, nullptr, h0, N0C);
    // K4: agg layer 0
    agg_kernel<<<(N1C + 3) / 4, 256, 0, stream>>>(h0, cnt0, ep0, comp0, T0, N1C);
    // K5: conv0 + LN + ReLU  (938 single-wave blocks)
    mfma_gemm<1, true, false, false, true><<<(N1C + 31) / 32, 64, 0, stream>>>(
        T0, 4, h0, wt + 1 * 16384, wt + 5 * 16384, bias0, g0, be0, h1, N1C);
    // K6: agg layer 1
    agg_kernel<<<(N2C + 3) / 4, 256, 0, stream>>>(h1, cnt1, ep1, comp1, T1, N2C);
    // K7: conv1 + LN + ReLU
    mfma_gemm<1, true, false, false, true><<<(N2C + 31) / 32, 64, 0, stream>>>(
        T1, 4, h1, wt + 6 * 16384, wt + 10 * 16384, bias1, g1, be1, h2, N2C);
    // K8: out = h2 @ postW + postb
    mfma_gemm<1, false, false, false, false><<<(N2C + 31) / 32, 64, 0, stream>>>(
        nullptr, 0, h2, nullptr, wt + 11 * 16384, postb, nullptr, nullptr, out, N2C);
}

// Round 8
// 297.245 us; speedup vs baseline: 4.8144x; 1.0263x over previous
//
#include <hip/hip_runtime.h>
#include <cstdint>

#define DD 128
#define CAP 64
#define E0C 480000
#define E1C 96000
#define N0C 120000
#define N1C 30000
#define N2C 6000

typedef unsigned short u16;
typedef __attribute__((ext_vector_type(8))) short bf16x8;
typedef __attribute__((ext_vector_type(16))) float f32x16;

__device__ __forceinline__ u16 f2b(float f) {
    union { float f; unsigned u; } a; a.f = f;
    unsigned r = (a.u + 0x7fffu + ((a.u >> 16) & 1u)) >> 16;
    return (u16)r;
}
__device__ __forceinline__ float b2f(u16 u) {
    union { unsigned u; float f; } a; a.u = ((unsigned)u) << 16;
    return a.f;
}

// ---- K1: weight convert+transpose into MFMA fragment order + zero counters ----
// wt layout (shorts): mat*16384 + kc*2048 + t*512 + half*256 + l31*8 + j
// where n = t*32+l31, k = kc*16+half*8+j. B-frag load in GEMM is then
// base + ((kc*4+t)*64 + lane)*8 -> lane-consecutive 16B, perfectly coalesced.
struct WtJob { const float* src[12]; };
__global__ __launch_bounds__(256) void prep_kernel(
    WtJob job, u16* __restrict__ dst, int* __restrict__ cnt0, int* __restrict__ cnt1)
{
    int gtid = blockIdx.x * 256 + threadIdx.x;
    for (int i = gtid; i < N1C + N2C; i += 256 * 256) {
        if (i < N1C) cnt0[i] = 0; else cnt1[i - N1C] = 0;
    }
    if (blockIdx.x >= 192) return;
    __shared__ float tile[32][33];
    int m = blockIdx.x >> 4;
    int t4 = blockIdx.x & 15;
    int tr = (t4 >> 2) * 32;   // k-base
    int tc = (t4 & 3) * 32;    // n-base
    int lx = threadIdx.x & 31, ly = threadIdx.x >> 5;
    #pragma unroll
    for (int yy = 0; yy < 32; yy += 8)
        tile[ly + yy][lx] = job.src[m][(tr + ly + yy) * DD + tc + lx];
    __syncthreads();
    int tid = threadIdx.x;
    if (tid < 128) {
        int nl = tid >> 2, kch = tid & 3;
        int k = tr + kch * 8, n = tc + nl;
        int kc = k >> 4, half = (k >> 3) & 1;
        int t = n >> 5, l31 = n & 31;
        bf16x8 pk;
        #pragma unroll
        for (int j = 0; j < 8; ++j) pk[j] = (short)f2b(tile[kch * 8 + j][nl]);
        *(bf16x8*)(dst + (size_t)m * 16384 + kc * 2048 + t * 512 + half * 256 + l31 * 8) = pk;
    }
}

// ---- K2: FUSED bucket-fill + pre-GEMM (independent work, no barrier needed) ----
// Each block: (a) grid-stride slice of all 576k edges -> atomic-append buckets;
// (b) its 4 m-tiles of h0 = relu(x @ preW + preb). Fill latency hides under
// the GEMM's BW streaming across the CU's resident waves.
__global__ __launch_bounds__(256) void pre_fill_kernel(
    const float* __restrict__ x,
    const int* __restrict__ src0, const int* __restrict__ dst0, const int* __restrict__ eid0,
    const int* __restrict__ src1, const int* __restrict__ dst1, const int* __restrict__ eid1,
    const int* __restrict__ etype,
    int* __restrict__ cnt0, int* __restrict__ cnt1,
    int* __restrict__ ep0, int* __restrict__ ep1,
    const u16* __restrict__ Wr, const float* __restrict__ bias,
    u16* __restrict__ h0)
{
    int gtid = blockIdx.x * 256 + threadIdx.x;
    int nthr = gridDim.x * 256;
    for (int e = gtid; e < E0C + E1C; e += nthr) {
        bool L0 = e < E0C;
        int ee = L0 ? e : e - E0C;
        int d   = L0 ? dst0[ee] : dst1[ee];
        int eid = L0 ? eid0[ee] : eid1[ee];
        int s   = L0 ? src0[ee] : src1[ee];
        int r = etype[eid];
        int* cnt = L0 ? cnt0 : cnt1;
        int* ep  = L0 ? ep0  : ep1;
        int pos = atomicAdd(&cnt[d], 1);
        if (pos < CAP) ep[(size_t)d * CAP + pos] = s | (r << 28);
    }

    int wave = threadIdx.x >> 6;
    int lane = threadIdx.x & 63;
    int l31 = lane & 31, half = lane >> 5;
    int ntile = (N0C + 31) >> 5;
    for (int tile = blockIdx.x * 4 + wave; tile < ntile; tile += gridDim.x * 4) {
        int m0 = tile * 32;
        int arow = m0 + l31;
        bool rv = arow < N0C;
        f32x16 acc[4];
        #pragma unroll
        for (int t = 0; t < 4; ++t)
            #pragma unroll
            for (int i = 0; i < 16; ++i) acc[t][i] = 0.f;

        const float* Aq = x + (size_t)arow * DD;
        float4 st[16];
        if (rv) {
            #pragma unroll
            for (int c = 0; c < 16; ++c)
                st[c] = *(const float4*)(Aq + ((c >> 1) * 16 + half * 8) + (c & 1) * 4);
        } else {
            #pragma unroll
            for (int c = 0; c < 16; ++c) st[c] = make_float4(0.f, 0.f, 0.f, 0.f);
        }
        #pragma unroll
        for (int kc = 0; kc < 8; ++kc) {
            bf16x8 bfr[4];
            #pragma unroll
            for (int t = 0; t < 4; ++t)
                bfr[t] = *(const bf16x8*)(Wr + (size_t)((kc * 4 + t) * 64 + lane) * 8);
            float4 u0 = st[2 * kc], u1 = st[2 * kc + 1];
            bf16x8 af;
            af[0] = (short)f2b(u0.x); af[1] = (short)f2b(u0.y);
            af[2] = (short)f2b(u0.z); af[3] = (short)f2b(u0.w);
            af[4] = (short)f2b(u1.x); af[5] = (short)f2b(u1.y);
            af[6] = (short)f2b(u1.z); af[7] = (short)f2b(u1.w);
            #pragma unroll
            for (int t = 0; t < 4; ++t)
                acc[t] = __builtin_amdgcn_mfma_f32_32x32x16_bf16(af, bfr[t], acc[t], 0, 0, 0);
        }

        float bb[4];
        #pragma unroll
        for (int t = 0; t < 4; ++t) bb[t] = bias[t * 32 + l31];
        #pragma unroll
        for (int reg = 0; reg < 16; ++reg) {
            int rl = (reg & 3) + 8 * (reg >> 2) + 4 * half;
            int row = m0 + rl;
            if (row < N0C) {
                #pragma unroll
                for (int t = 0; t < 4; ++t)
                    ((u16*)h0)[(size_t)row * DD + t * 32 + l31] =
                        f2b(fmaxf(acc[t][reg] + bb[t], 0.f));
            }
        }
    }
}

// ---- gather-aggregate into 4 basis planes, 1/deg folded in ----
__global__ __launch_bounds__(256) void agg_kernel(
    const u16* __restrict__ h, const int* __restrict__ cnt,
    const int* __restrict__ ep, const float* __restrict__ comp,
    u16* __restrict__ T, int ndst)
{
    __shared__ float4 cmp4[8];
    if (threadIdx.x < 8) cmp4[threadIdx.x] = ((const float4*)comp)[threadIdx.x];
    __syncthreads();
    int row = blockIdx.x * 4 + (threadIdx.x >> 6);
    if (row >= ndst) return;
    int lane = threadIdx.x & 63;
    int n = cnt[row];
    int end = n < CAP ? n : CAP;
    const int* erow = ep + (size_t)row * CAP;
    float a0[4] = {0.f, 0.f, 0.f, 0.f};
    float a1[4] = {0.f, 0.f, 0.f, 0.f};
    int j = 0;
    for (; j + 8 <= end; j += 8) {
        int vv[8]; unsigned gg[8];
        #pragma unroll
        for (int u = 0; u < 8; ++u) vv[u] = erow[j + u];
        #pragma unroll
        for (int u = 0; u < 8; ++u)
            gg[u] = *(const unsigned*)(h + (size_t)(vv[u] & 0x0FFFFFFF) * DD + 2 * lane);
        #pragma unroll
        for (int u = 0; u < 8; ++u) {
            float4 c = cmp4[vv[u] >> 28];
            float x0 = b2f((u16)(gg[u] & 0xffffu));
            float x1 = b2f((u16)(gg[u] >> 16));
            a0[0] = fmaf(c.x, x0, a0[0]); a1[0] = fmaf(c.x, x1, a1[0]);
            a0[1] = fmaf(c.y, x0, a0[1]); a1[1] = fmaf(c.y, x1, a1[1]);
            a0[2] = fmaf(c.z, x0, a0[2]); a1[2] = fmaf(c.z, x1, a1[2]);
            a0[3] = fmaf(c.w, x0, a0[3]); a1[3] = fmaf(c.w, x1, a1[3]);
        }
    }
    for (; j < end; ++j) {
        int v = erow[j];
        unsigned g = *(const unsigned*)(h + (size_t)(v & 0x0FFFFFFF) * DD + 2 * lane);
        float4 c = cmp4[v >> 28];
        float x0 = b2f((u16)(g & 0xffffu));
        float x1 = b2f((u16)(g >> 16));
        a0[0] = fmaf(c.x, x0, a0[0]); a1[0] = fmaf(c.x, x1, a1[0]);
        a0[1] = fmaf(c.y, x0, a0[1]); a1[1] = fmaf(c.y, x1, a1[1]);
        a0[2] = fmaf(c.z, x0, a0[2]); a1[2] = fmaf(c.z, x1, a1[2]);
        a0[3] = fmaf(c.w, x0, a0[3]); a1[3] = fmaf(c.w, x1, a1[3]);
    }
    float inv = 1.f / fmaxf((float)n, 1.f);
    #pragma unroll
    for (int b = 0; b < 4; ++b) {
        unsigned pk = (unsigned)f2b(a0[b] * inv) | ((unsigned)f2b(a1[b] * inv) << 16);
        *(unsigned*)(T + ((size_t)b * ndst + row) * DD + 2 * lane) = pk;
    }
}

// ---- 32x32x16 MFMA GEMM, one 32-row m-tile per wave, A prefetched ----
// C[nrows x 128] = sum_p Ap[p]@Wp[p] + Ar@Wr + bias, optional LN/ReLU.
// W in fragment order (see prep). A: [row][k].
// C/D layout: col=lane&31, row=(reg&3)+8*(reg>>2)+4*(lane>>5)  [m74/m101].
template<int WPB, bool OBF16, bool LN>
__global__ __launch_bounds__(WPB * 64) void mfma_gemm(
    const u16* __restrict__ Ap, int nplanes, const u16* __restrict__ Ar,
    const u16* __restrict__ Wp, const u16* __restrict__ Wr,
    const float* __restrict__ bias, const float* __restrict__ gw,
    const float* __restrict__ bw, void* __restrict__ Cv, int nrows)
{
    int wave = threadIdx.x >> 6;
    int lane = threadIdx.x & 63;
    int l31 = lane & 31, half = lane >> 5;
    int m0 = (blockIdx.x * WPB + wave) * 32;
    int arow = m0 + l31;
    bool rv = arow < nrows;
    f32x16 acc[4];
    #pragma unroll
    for (int t = 0; t < 4; ++t)
        #pragma unroll
        for (int i = 0; i < 16; ++i) acc[t][i] = 0.f;

    bf16x8 A0[8], A1[8];
    {
        const u16* Ainit = (nplanes == 0) ? Ar : Ap;
        if (rv) {
            #pragma unroll
            for (int c = 0; c < 8; ++c)
                A0[c] = *(const bf16x8*)(Ainit + (size_t)arow * DD + c * 16 + half * 8);
        } else {
            #pragma unroll
            for (int c = 0; c < 8; ++c) A0[c] = (bf16x8){0,0,0,0,0,0,0,0};
        }
    }
    for (int p = 0; p <= nplanes; ++p) {
        const u16* Wsel = (p == nplanes) ? Wr : Wp + p * 16384;
        if (p < nplanes) {
            const u16* An = (p + 1 == nplanes) ? Ar : Ap + (size_t)(p + 1) * nrows * DD;
            if (rv) {
                #pragma unroll
                for (int c = 0; c < 8; ++c)
                    A1[c] = *(const bf16x8*)(An + (size_t)arow * DD + c * 16 + half * 8);
            } else {
                #pragma unroll
                for (int c = 0; c < 8; ++c) A1[c] = (bf16x8){0,0,0,0,0,0,0,0};
            }
        }
        #pragma unroll
        for (int kc = 0; kc < 8; ++kc) {
            bf16x8 bfr[4];
            #pragma unroll
            for (int t = 0; t < 4; ++t)
                bfr[t] = *(const bf16x8*)(Wsel + (size_t)((kc * 4 + t) * 64 + lane) * 8);
            #pragma unroll
            for (int t = 0; t < 4; ++t)
                acc[t] = __builtin_amdgcn_mfma_f32_32x32x16_bf16(A0[kc], bfr[t], acc[t], 0, 0, 0);
        }
        if (p < nplanes) {
            #pragma unroll
            for (int c = 0; c < 8; ++c) A0[c] = A1[c];
        }
    }

    float bb[4];
    #pragma unroll
    for (int t = 0; t < 4; ++t) bb[t] = bias[t * 32 + l31];
    float gg[4], ww[4];
    if (LN) {
        #pragma unroll
        for (int t = 0; t < 4; ++t) { gg[t] = gw[t * 32 + l31]; ww[t] = bw[t * 32 + l31]; }
    }

    #pragma unroll
    for (int reg = 0; reg < 16; ++reg) {
        int rl = (reg & 3) + 8 * (reg >> 2) + 4 * half;
        int row = m0 + rl;
        float v[4];
        #pragma unroll
        for (int t = 0; t < 4; ++t) v[t] = acc[t][reg] + bb[t];
        if (LN) {
            float s1 = 0.f, s2 = 0.f;
            #pragma unroll
            for (int t = 0; t < 4; ++t) { s1 += v[t]; s2 += v[t] * v[t]; }
            #pragma unroll
            for (int o = 1; o < 32; o <<= 1) {
                s1 += __shfl_xor(s1, o);
                s2 += __shfl_xor(s2, o);
            }
            float mu = s1 * (1.f / 128.f);
            float var = s2 * (1.f / 128.f) - mu * mu;
            float rstd = rsqrtf(fmaxf(var, 0.f) + 1e-5f);
            #pragma unroll
            for (int t = 0; t < 4; ++t)
                v[t] = fmaxf((v[t] - mu) * rstd * gg[t] + ww[t], 0.f);
        }
        if (row < nrows) {
            #pragma unroll
            for (int t = 0; t < 4; ++t) {
                if (OBF16) ((u16*)Cv)[(size_t)row * DD + t * 32 + l31] = f2b(v[t]);
                else       ((float*)Cv)[(size_t)row * DD + t * 32 + l31] = v[t];
            }
        }
    }
}

extern "C" void kernel_launch(void* const* d_in, const int* in_sizes, int n_in,
                              void* d_out, int out_size, void* d_ws, size_t ws_size,
                              hipStream_t stream)
{
    const float* x     = (const float*)d_in[0];
    const int* src0    = (const int*)d_in[1];
    const int* dst0    = (const int*)d_in[2];
    const int* eid0    = (const int*)d_in[3];
    const int* src1    = (const int*)d_in[4];
    const int* dst1    = (const int*)d_in[5];
    const int* eid1    = (const int*)d_in[6];
    const int* etype   = (const int*)d_in[7];
    const float* preW  = (const float*)d_in[8];
    const float* preb  = (const float*)d_in[9];
    const float* basis0 = (const float*)d_in[10];
    const float* comp0  = (const float*)d_in[11];
    const float* root0  = (const float*)d_in[12];
    const float* bias0  = (const float*)d_in[13];
    const float* g0    = (const float*)d_in[14];
    const float* be0   = (const float*)d_in[15];
    const float* basis1 = (const float*)d_in[16];
    const float* comp1  = (const float*)d_in[17];
    const float* root1  = (const float*)d_in[18];
    const float* bias1  = (const float*)d_in[19];
    const float* g1    = (const float*)d_in[20];
    const float* be1   = (const float*)d_in[21];
    const float* postW = (const float*)d_in[22];
    const float* postb = (const float*)d_in[23];
    float* out = (float*)d_out;

    char* ws = (char*)d_ws;
    size_t o = 0;
    auto alloc = [&](size_t bytes) { char* p = ws + o; o += (bytes + 255) & ~(size_t)255; return p; };
    u16* h0   = (u16*)alloc((size_t)N0C * DD * 2);
    u16* T0   = (u16*)alloc((size_t)4 * N1C * DD * 2);
    u16* h1   = (u16*)alloc((size_t)N1C * DD * 2);
    u16* T1   = (u16*)alloc((size_t)4 * N2C * DD * 2);
    u16* h2   = (u16*)alloc((size_t)N2C * DD * 2);
    u16* wt   = (u16*)alloc((size_t)12 * 16384 * 2);
    int* cnt0 = (int*)alloc((size_t)N1C * 4);
    int* cnt1 = (int*)alloc((size_t)N2C * 4);
    int* ep0  = (int*)alloc((size_t)N1C * CAP * 4);
    int* ep1  = (int*)alloc((size_t)N2C * CAP * 4);

    // wt layout: [0]=pre, [1..4]=basis0, [5]=root0, [6..9]=basis1, [10]=root1, [11]=post
    WtJob job;
    job.src[0] = preW;
    for (int b = 0; b < 4; ++b) job.src[1 + b] = basis0 + (size_t)b * 16384;
    job.src[5] = root0;
    for (int b = 0; b < 4; ++b) job.src[6 + b] = basis1 + (size_t)b * 16384;
    job.src[10] = root1;
    job.src[11] = postW;

    // K1: weight transpose + zero counters
    prep_kernel<<<256, 256, 0, stream>>>(job, wt, cnt0, cnt1);
    // K2: fused bucket-fill + pre-GEMM
    pre_fill_kernel<<<(N0C + 127) / 128, 256, 0, stream>>>(
        x, src0, dst0, eid0, src1, dst1, eid1, etype,
        cnt0, cnt1, ep0, ep1, wt + 0 * 16384, preb, h0);
    // K3: agg layer 0
    agg_kernel<<<(N1C + 3) / 4, 256, 0, stream>>>(h0, cnt0, ep0, comp0, T0, N1C);
    // K4: conv0 + LN + ReLU  (938 single-wave blocks)
    mfma_gemm<1, true, true><<<(N1C + 31) / 32, 64, 0, stream>>>(
        T0, 4, h0, wt + 1 * 16384, wt + 5 * 16384, bias0, g0, be0, h1, N1C);
    // K5: agg layer 1
    agg_kernel<<<(N2C + 3) / 4, 256, 0, stream>>>(h1, cnt1, ep1, comp1, T1, N2C);
    // K6: conv1 + LN + ReLU
    mfma_gemm<1, true, true><<<(N2C + 31) / 32, 64, 0, stream>>>(
        T1, 4, h1, wt + 6 * 16384, wt + 10 * 16384, bias1, g1, be1, h2, N2C);
    // K7: out = h2 @ postW + postb
    mfma_gemm<1, false, false><<<(N2C + 31) / 32, 64, 0, stream>>>(
        nullptr, 0, h2, nullptr, wt + 11 * 16384, postb, nullptr, nullptr, out, N2C);
}